// Round 7
// baseline (5940.858 us; speedup 1.0000x reference)
//
#include <hip/hip_runtime.h>
#include <hip/hip_bf16.h>
#include <hip/hip_fp16.h>

// Problem constants (fixed by the reference)
constexpr int NNODES = 200000;   // 4 graphs x 50000
constexpr int NGRAPH_NODES = 50000;
constexpr int NE = 3200000;
constexpr int H = 64;
constexpr int NCB = NNODES / 64;             // 3125 coarse buckets (64 nodes each)
constexpr unsigned SRC_MASK = 0x3FFFFu;      // 18 bits

// ---------------------------------------------------------------------------
// Fused 3-GEMM per inception block: Y = X@Wl + (Bl+B1+B2), S1 = X@W1, S2 = X@W2
// TS = storage type for S1/S2 (fp16 on the fast path to halve gather bytes).
// ---------------------------------------------------------------------------
template <int DI, typename TS>
__global__ __launch_bounds__(256) void gemm3_kernel(
    const float* __restrict__ X,
    const float* __restrict__ Wl, const float* __restrict__ Bl,
    const float* __restrict__ W1, const float* __restrict__ B1,
    const float* __restrict__ W2, const float* __restrict__ B2,
    float* __restrict__ Y, TS* __restrict__ S1, TS* __restrict__ S2)
{
    __shared__ float xs[32][DI];
    const int tid = threadIdx.x;
    const int f = tid & 63;
    const int r = tid >> 6;
    const int base = blockIdx.x * 32;

    const float4* xg = reinterpret_cast<const float4*>(X + (size_t)base * DI);
    float4* xsv = reinterpret_cast<float4*>(&xs[0][0]);
    constexpr int NV = 32 * DI / 4;
    #pragma unroll
    for (int i = tid; i < NV; i += 256) xsv[i] = xg[i];
    __syncthreads();

    float accL[8], acc1[8], acc2[8];
    #pragma unroll
    for (int i = 0; i < 8; ++i) { accL[i] = 0.f; acc1[i] = 0.f; acc2[i] = 0.f; }

    for (int k = 0; k < DI; ++k) {
        float wl = Wl[k * H + f];
        float w1 = W1[k * H + f];
        float w2 = W2[k * H + f];
        #pragma unroll
        for (int i = 0; i < 8; ++i) {
            float xv = xs[r * 8 + i][k];
            accL[i] = fmaf(xv, wl, accL[i]);
            acc1[i] = fmaf(xv, w1, acc1[i]);
            acc2[i] = fmaf(xv, w2, acc2[i]);
        }
    }

    float bias = Bl[f] + B1[f] + B2[f];
    #pragma unroll
    for (int i = 0; i < 8; ++i) {
        size_t n = (size_t)(base + r * 8 + i);
        Y[n * H + f]  = accL[i] + bias;
        S1[n * H + f] = (TS)acc1[i];
        S2[n * H + f] = (TS)acc2[i];
    }
}

// ---------------------------------------------------------------------------
// Block 3 GEMM (DI=64 -> DO=1): three dot products per node.
// ---------------------------------------------------------------------------
__global__ __launch_bounds__(256) void gemm3_out1_kernel(
    const float* __restrict__ X,
    const float* __restrict__ Wl, const float* __restrict__ Bl,
    const float* __restrict__ W1, const float* __restrict__ B1,
    const float* __restrict__ W2, const float* __restrict__ B2,
    float* __restrict__ Y, float* __restrict__ S1, float* __restrict__ S2)
{
    __shared__ float wls[64], w1s[64], w2s[64];
    const int tid = threadIdx.x;
    if (tid < 64) { wls[tid] = Wl[tid]; w1s[tid] = W1[tid]; w2s[tid] = W2[tid]; }
    __syncthreads();
    const int n = blockIdx.x * 256 + tid;
    if (n >= NNODES) return;
    const float4* xr = reinterpret_cast<const float4*>(X + (size_t)n * H);
    float aL = 0.f, a1 = 0.f, a2 = 0.f;
    #pragma unroll
    for (int kv = 0; kv < 16; ++kv) {
        float4 xv = xr[kv];
        int k = kv * 4;
        aL = fmaf(xv.x, wls[k + 0], aL); a1 = fmaf(xv.x, w1s[k + 0], a1); a2 = fmaf(xv.x, w2s[k + 0], a2);
        aL = fmaf(xv.y, wls[k + 1], aL); a1 = fmaf(xv.y, w1s[k + 1], a1); a2 = fmaf(xv.y, w2s[k + 1], a2);
        aL = fmaf(xv.z, wls[k + 2], aL); a1 = fmaf(xv.z, w1s[k + 2], a1); a2 = fmaf(xv.z, w2s[k + 2], a2);
        aL = fmaf(xv.w, wls[k + 3], aL); a1 = fmaf(xv.w, w1s[k + 3], a1); a2 = fmaf(xv.w, w2s[k + 3], a2);
    }
    float bias = Bl[0] + B1[0] + B2[0];
    Y[n] = aL + bias; S1[n] = a1; S2[n] = a2;
}

// ---------------------------------------------------------------------------
// Coarse counting sort: 3125 buckets of 64 nodes. Frontier (6250 cursor lines,
// ~400 KB) is L2-resident -> sorted-array writes fill whole lines (no 8x
// write amplification). Entry: (src | dstLow<<18, w_fp32).
// ---------------------------------------------------------------------------
__global__ __launch_bounds__(256) void hist_coarse_kernel(
    const int* __restrict__ dst1, const int* __restrict__ dst2,
    int* __restrict__ cnt)   // cnt[2*NCB]
{
    const int* dst = blockIdx.y ? dst2 : dst1;
    int* c = cnt + blockIdx.y * NCB;
    const int t = blockIdx.x * 256 + threadIdx.x;
    const int tot = gridDim.x * 256;
    const int4* d4 = reinterpret_cast<const int4*>(dst);
    for (int q = t; q < NE / 4; q += tot) {
        int4 v = d4[q];
        atomicAdd(&c[v.x >> 6], 1);
        atomicAdd(&c[v.y >> 6], 1);
        atomicAdd(&c[v.z >> 6], 1);
        atomicAdd(&c[v.w >> 6], 1);
    }
}

// Exclusive scan of 3125 counts per set (one block per set).
__global__ __launch_bounds__(1024) void scan_coarse_kernel(
    const int* __restrict__ cnt, int* __restrict__ cbase, int* __restrict__ ccur)
{
    const int set = blockIdx.x;
    const int* c = cnt + set * NCB;
    int* b = cbase + set * (NCB + 1);
    int* cu = ccur + set * NCB;
    __shared__ int part[1024];
    const int t = threadIdx.x;
    const int lo = t * 4;
    int v[4]; int s = 0;
    #pragma unroll
    for (int j = 0; j < 4; ++j) {
        int i = lo + j;
        v[j] = (i < NCB) ? c[i] : 0;
        s += v[j];
    }
    part[t] = s;
    __syncthreads();
    for (int off = 1; off < 1024; off <<= 1) {
        int u = (t >= off) ? part[t - off] : 0;
        __syncthreads();
        part[t] += u;
        __syncthreads();
    }
    int run = part[t] - s;   // exclusive chunk prefix
    #pragma unroll
    for (int j = 0; j < 4; ++j) {
        int i = lo + j;
        if (i < NCB) { b[i] = run; cu[i] = run; run += v[j]; }
    }
    if (t == 1023) b[NCB] = part[1023];
}

__global__ __launch_bounds__(256) void place_coarse_kernel(
    const int* __restrict__ ei1, const float* __restrict__ ew1,
    const int* __restrict__ ei2, const float* __restrict__ ew2,
    int* __restrict__ ccur, uint2* __restrict__ E1, uint2* __restrict__ E2)
{
    const int set = blockIdx.y;
    const int* EI = set ? ei2 : ei1;
    const float* EW = set ? ew2 : ew1;
    int* cur = ccur + set * NCB;
    uint2* E = set ? E2 : E1;
    const int t = blockIdx.x * 256 + threadIdx.x;
    const int tot = gridDim.x * 256;
    const int4* s4 = reinterpret_cast<const int4*>(EI);
    const int4* d4 = reinterpret_cast<const int4*>(EI + NE);
    const float4* w4 = reinterpret_cast<const float4*>(EW);
    for (int q = t; q < NE / 4; q += tot) {
        int4 s = s4[q];
        int4 d = d4[q];
        float4 w = w4[q];
        int p0 = atomicAdd(&cur[d.x >> 6], 1);
        int p1 = atomicAdd(&cur[d.y >> 6], 1);
        int p2 = atomicAdd(&cur[d.z >> 6], 1);
        int p3 = atomicAdd(&cur[d.w >> 6], 1);
        E[p0] = make_uint2((unsigned)s.x | ((unsigned)(d.x & 63) << 18), __float_as_uint(w.x));
        E[p1] = make_uint2((unsigned)s.y | ((unsigned)(d.y & 63) << 18), __float_as_uint(w.y));
        E[p2] = make_uint2((unsigned)s.z | ((unsigned)(d.z & 63) << 18), __float_as_uint(w.z));
        E[p3] = make_uint2((unsigned)s.w | ((unsigned)(d.w & 63) << 18), __float_as_uint(w.w));
    }
}

// ---------------------------------------------------------------------------
// Bucket aggregation, 64 features: one block per 64-node bucket.
// LDS accumulator [64 nodes][64 feat] f32 = 16 KB -> 8 blocks/CU.
// Lane = feature; ds_add_f32 per edge (lanes hit distinct addresses).
// Exclusive bucket ownership -> plain Y += writeout.
// ---------------------------------------------------------------------------
__global__ __launch_bounds__(256) void bucket_accum64_kernel(
    const uint2* __restrict__ E1, const int* __restrict__ cb1,
    const uint2* __restrict__ E2, const int* __restrict__ cb2,
    const __half* __restrict__ S1, const __half* __restrict__ S2,
    float* __restrict__ Y)
{
    __shared__ float acc[64 * 64];
    const int tid = threadIdx.x;
    const int lane = tid & 63;
    const int wave = tid >> 6;   // 0..3
    const int b = blockIdx.x;

    float4* a4 = reinterpret_cast<float4*>(acc);
    #pragma unroll
    for (int i = tid; i < 64 * 16; i += 256) a4[i] = make_float4(0.f, 0.f, 0.f, 0.f);
    __syncthreads();

    #pragma unroll
    for (int set = 0; set < 2; ++set) {
        const uint2* E = set ? E2 : E1;
        const __half* S = set ? S2 : S1;
        const int* cb = set ? cb2 : cb1;
        const int lo = cb[b];
        const int n = cb[b + 1] - lo;
        int i = wave;
        // 8-deep batches, 4 waves interleaved at stride 4
        for (; i + 28 < n; i += 32) {
            uint2 p[8];
            float v[8];
            #pragma unroll
            for (int j = 0; j < 8; ++j) p[j] = E[lo + i + 4 * j];
            #pragma unroll
            for (int j = 0; j < 8; ++j)
                v[j] = __half2float(S[(size_t)(p[j].x & SRC_MASK) * H + lane]);
            #pragma unroll
            for (int j = 0; j < 8; ++j)
                atomicAdd(&acc[((p[j].x >> 18) & 63) * 64 + lane],
                          __uint_as_float(p[j].y) * v[j]);
        }
        for (; i < n; i += 4) {
            uint2 p = E[lo + i];
            float v = __half2float(S[(size_t)(p.x & SRC_MASK) * H + lane]);
            atomicAdd(&acc[((p.x >> 18) & 63) * 64 + lane],
                      __uint_as_float(p.y) * v);
        }
    }
    __syncthreads();

    #pragma unroll
    for (int r = wave; r < 64; r += 4) {
        size_t idx = ((size_t)b * 64 + r) * H + lane;
        Y[idx] += acc[r * 64 + lane];
    }
}

// ---------------------------------------------------------------------------
// Block-3 bucket aggregation (scalar, fp32) + fused readout.
// ---------------------------------------------------------------------------
__device__ __forceinline__ unsigned fkey(float v) {
    unsigned u = __float_as_uint(v);
    return (u & 0x80000000u) ? ~u : (u | 0x80000000u);
}

__global__ __launch_bounds__(256) void bucket_accum1_readout_kernel(
    const uint2* __restrict__ E1, const int* __restrict__ cb1,
    const uint2* __restrict__ E2, const int* __restrict__ cb2,
    const float* __restrict__ s1, const float* __restrict__ s2,
    const float* __restrict__ Y3,
    float* __restrict__ body1, float* __restrict__ body2,
    unsigned int* __restrict__ keys)
{
    __shared__ float facc[64];
    __shared__ unsigned karr[64];
    const int tid = threadIdx.x;
    const int b = blockIdx.x;
    if (tid < 64) facc[tid] = 0.f;
    __syncthreads();

    #pragma unroll
    for (int set = 0; set < 2; ++set) {
        const uint2* E = set ? E2 : E1;
        const float* s = set ? s2 : s1;
        const int* cb = set ? cb2 : cb1;
        const int lo = cb[b], hi = cb[b + 1];
        for (int e = lo + tid; e < hi; e += 256) {
            uint2 p = E[e];
            atomicAdd(&facc[(p.x >> 18) & 63],
                      __uint_as_float(p.y) * s[p.x & SRC_MASK]);
        }
    }
    __syncthreads();

    if (tid < 64) {
        int node = b * 64 + tid;
        float v = Y3[node] + facc[tid];
        body1[node] = v;
        body2[node] = v;
        karr[tid] = fkey(v);
    }
    __syncthreads();
    if (tid == 0) {
        // bucket may straddle a graph boundary (50000 % 64 != 0)
        int g0 = (b * 64) / NGRAPH_NODES;
        unsigned m0 = 0, m1 = 0;
        for (int i = 0; i < 64; ++i) {
            int g = (b * 64 + i) / NGRAPH_NODES;
            if (g == g0) m0 = max(m0, karr[i]); else m1 = max(m1, karr[i]);
        }
        if (m0) atomicMax(&keys[g0], m0);
        if (m1) atomicMax(&keys[g0 + 1], m1);
    }
}

__global__ void finalize_kernel(const unsigned int* __restrict__ keys,
                                float* __restrict__ out)
{
    int i = threadIdx.x;
    if (i < 4) {
        unsigned k = keys[i];
        unsigned u = (k & 0x80000000u) ? (k ^ 0x80000000u) : ~k;
        out[i] = __uint_as_float(u);
    }
}

// ---------------------------------------------------------------------------
// Fallback (atomic) scatters — used only if ws_size is too small.
// ---------------------------------------------------------------------------
__global__ __launch_bounds__(256) void scatter64_kernel(
    const int* __restrict__ EI, const float* __restrict__ EW,
    const float* __restrict__ S, float* __restrict__ Y)
{
    const int lane = threadIdx.x & 63;
    const int wid = (blockIdx.x * 256 + threadIdx.x) >> 6;
    const int nw = (gridDim.x * 256) >> 6;
    for (int e = wid; e < NE; e += nw) {
        int s = EI[e];
        int d = EI[NE + e];
        float w = EW[e];
        float v = S[(size_t)s * H + lane];
        unsafeAtomicAdd(&Y[(size_t)d * H + lane], w * v);
    }
}

__global__ __launch_bounds__(256) void scatter1_kernel(
    const int* __restrict__ EI, const float* __restrict__ EW,
    const float* __restrict__ S, float* __restrict__ Y)
{
    const int t = blockIdx.x * 256 + threadIdx.x;
    const int tot = gridDim.x * 256;
    for (int e = t; e < NE; e += tot) {
        int s = EI[e];
        int d = EI[NE + e];
        float w = EW[e];
        unsafeAtomicAdd(&Y[d], w * S[s]);
    }
}

__global__ __launch_bounds__(256) void readout_kernel(
    const float* __restrict__ Y3, float* __restrict__ body1,
    float* __restrict__ body2, unsigned int* __restrict__ keys)
{
    __shared__ unsigned int smax[4];
    const int tid = threadIdx.x;
    if (tid < 4) smax[tid] = 0u;
    __syncthreads();
    const int i = blockIdx.x * 256 + tid;
    if (i < NNODES) {
        float v = Y3[i];
        body1[i] = v;
        body2[i] = v;
        atomicMax(&smax[i / NGRAPH_NODES], fkey(v));
    }
    __syncthreads();
    if (tid < 4 && smax[tid]) atomicMax(&keys[tid], smax[tid]);
}

// ---------------------------------------------------------------------------
extern "C" void kernel_launch(void* const* d_in, const int* in_sizes, int n_in,
                              void* d_out, int out_size, void* d_ws, size_t ws_size,
                              hipStream_t stream)
{
    const float* x   = (const float*)d_in[0];
    const int*   ei  = (const int*)d_in[1];
    const float* ew  = (const float*)d_in[2];
    const int*   ei2 = (const int*)d_in[3];
    const float* ew2 = (const float*)d_in[4];
    const float* W[18];
    for (int i = 0; i < 18; ++i) W[i] = (const float*)d_in[6 + i];

    // S1/S2 sized for the fp32 fallback (fp16 fast path uses half the space)
    float* Y  = (float*)d_ws;                       // 200000 x 64 f32
    float* S1 = Y + (size_t)NNODES * H;             // 200000 x 64 f32 (or f16)
    float* S2 = S1 + (size_t)NNODES * H;
    float* Y3 = S2 + (size_t)NNODES * H;            // 200000 f32
    uint2* E1 = (uint2*)(Y3 + NNODES);              // NE uint2
    uint2* E2 = E1 + NE;
    unsigned int* keys = (unsigned int*)(E2 + NE);  // 4
    int* cnt   = (int*)(keys + 4);                  // 2*NCB
    int* cbase = cnt + 2 * NCB;                     // 2*(NCB+1)
    int* ccur  = cbase + 2 * (NCB + 1);             // 2*NCB
    size_t needed = (size_t)((char*)(ccur + 2 * NCB) - (char*)d_ws);

    __half* hS1 = (__half*)S1;
    __half* hS2 = (__half*)S2;

    int* cb1 = cbase;
    int* cb2 = cbase + (NCB + 1);

    float* out = (float*)d_out;   // [0..3]=graph max, then x twice

    if (ws_size >= needed) {
        // zero keys + coarse histograms in one memset
        hipMemsetAsync(keys, 0, (size_t)(4 + 2 * NCB) * sizeof(int), stream);

        // Coarse counting sort (64-node buckets), reused by all 3 blocks
        hist_coarse_kernel<<<dim3(1024, 2), 256, 0, stream>>>(ei + NE, ei2 + NE, cnt);
        scan_coarse_kernel<<<2, 1024, 0, stream>>>(cnt, cbase, ccur);
        place_coarse_kernel<<<dim3(1024, 2), 256, 0, stream>>>(
            ei, ew, ei2, ew2, ccur, E1, E2);

        // Block 1
        gemm3_kernel<128, __half><<<NNODES / 32, 256, 0, stream>>>(
            x, W[0], W[1], W[2], W[3], W[4], W[5], Y, hS1, hS2);
        bucket_accum64_kernel<<<NCB, 256, 0, stream>>>(E1, cb1, E2, cb2, hS1, hS2, Y);

        // Block 2 (in-place on Y)
        gemm3_kernel<64, __half><<<NNODES / 32, 256, 0, stream>>>(
            Y, W[6], W[7], W[8], W[9], W[10], W[11], Y, hS1, hS2);
        bucket_accum64_kernel<<<NCB, 256, 0, stream>>>(E1, cb1, E2, cb2, hS1, hS2, Y);

        // Block 3 (S1/S2 reused as [NNODES] f32 scalars) + fused readout
        gemm3_out1_kernel<<<(NNODES + 255) / 256, 256, 0, stream>>>(
            Y, W[12], W[13], W[14], W[15], W[16], W[17], Y3, S1, S2);
        bucket_accum1_readout_kernel<<<NCB, 256, 0, stream>>>(
            E1, cb1, E2, cb2, S1, S2, Y3, out + 4, out + 4 + NNODES, keys);
        finalize_kernel<<<1, 64, 0, stream>>>(keys, out);
    } else {
        unsigned int* okeys = (unsigned int*)(Y3 + NNODES);
        hipMemsetAsync(okeys, 0, 4 * sizeof(unsigned int), stream);

        gemm3_kernel<128, float><<<NNODES / 32, 256, 0, stream>>>(
            x, W[0], W[1], W[2], W[3], W[4], W[5], Y, S1, S2);
        scatter64_kernel<<<2048, 256, 0, stream>>>(ei,  ew,  S1, Y);
        scatter64_kernel<<<2048, 256, 0, stream>>>(ei2, ew2, S2, Y);

        gemm3_kernel<64, float><<<NNODES / 32, 256, 0, stream>>>(
            Y, W[6], W[7], W[8], W[9], W[10], W[11], Y, S1, S2);
        scatter64_kernel<<<2048, 256, 0, stream>>>(ei,  ew,  S1, Y);
        scatter64_kernel<<<2048, 256, 0, stream>>>(ei2, ew2, S2, Y);

        gemm3_out1_kernel<<<(NNODES + 255) / 256, 256, 0, stream>>>(
            Y, W[12], W[13], W[14], W[15], W[16], W[17], Y3, S1, S2);
        scatter1_kernel<<<2048, 256, 0, stream>>>(ei,  ew,  S1, Y3);
        scatter1_kernel<<<2048, 256, 0, stream>>>(ei2, ew2, S2, Y3);

        readout_kernel<<<(NNODES + 255) / 256, 256, 0, stream>>>(
            Y3, out + 4, out + 4 + NNODES, okeys);
        finalize_kernel<<<1, 64, 0, stream>>>(okeys, out);
    }
}

// Round 8
// 2137.406 us; speedup vs baseline: 2.7795x; 2.7795x over previous
//
#include <hip/hip_runtime.h>
#include <hip/hip_bf16.h>
#include <hip/hip_fp16.h>

// Problem constants (fixed by the reference)
constexpr int NNODES = 200000;   // 4 graphs x 50000
constexpr int NGRAPH_NODES = 50000;
constexpr int NE = 3200000;
constexpr int H = 64;
constexpr int NCB = NNODES / 64;             // 3125 coarse buckets (64 nodes each)
constexpr unsigned SRC_MASK = 0x3FFFFu;      // 18 bits
constexpr int RCAP = 2560;                   // refine staging capacity (avg 1024, 48 sigma)

// ---------------------------------------------------------------------------
// Fused 3-GEMM per inception block: Y = X@Wl + (Bl+B1+B2), S1 = X@W1, S2 = X@W2
// TS = storage type for S1/S2 (fp16 on the fast path to halve gather bytes).
// ---------------------------------------------------------------------------
template <int DI, typename TS>
__global__ __launch_bounds__(256) void gemm3_kernel(
    const float* __restrict__ X,
    const float* __restrict__ Wl, const float* __restrict__ Bl,
    const float* __restrict__ W1, const float* __restrict__ B1,
    const float* __restrict__ W2, const float* __restrict__ B2,
    float* __restrict__ Y, TS* __restrict__ S1, TS* __restrict__ S2)
{
    __shared__ float xs[32][DI];
    const int tid = threadIdx.x;
    const int f = tid & 63;
    const int r = tid >> 6;
    const int base = blockIdx.x * 32;

    const float4* xg = reinterpret_cast<const float4*>(X + (size_t)base * DI);
    float4* xsv = reinterpret_cast<float4*>(&xs[0][0]);
    constexpr int NV = 32 * DI / 4;
    #pragma unroll
    for (int i = tid; i < NV; i += 256) xsv[i] = xg[i];
    __syncthreads();

    float accL[8], acc1[8], acc2[8];
    #pragma unroll
    for (int i = 0; i < 8; ++i) { accL[i] = 0.f; acc1[i] = 0.f; acc2[i] = 0.f; }

    for (int k = 0; k < DI; ++k) {
        float wl = Wl[k * H + f];
        float w1 = W1[k * H + f];
        float w2 = W2[k * H + f];
        #pragma unroll
        for (int i = 0; i < 8; ++i) {
            float xv = xs[r * 8 + i][k];
            accL[i] = fmaf(xv, wl, accL[i]);
            acc1[i] = fmaf(xv, w1, acc1[i]);
            acc2[i] = fmaf(xv, w2, acc2[i]);
        }
    }

    float bias = Bl[f] + B1[f] + B2[f];
    #pragma unroll
    for (int i = 0; i < 8; ++i) {
        size_t n = (size_t)(base + r * 8 + i);
        Y[n * H + f]  = accL[i] + bias;
        S1[n * H + f] = (TS)acc1[i];
        S2[n * H + f] = (TS)acc2[i];
    }
}

// ---------------------------------------------------------------------------
// Block 3 GEMM (DI=64 -> DO=1): three dot products per node.
// ---------------------------------------------------------------------------
__global__ __launch_bounds__(256) void gemm3_out1_kernel(
    const float* __restrict__ X,
    const float* __restrict__ Wl, const float* __restrict__ Bl,
    const float* __restrict__ W1, const float* __restrict__ B1,
    const float* __restrict__ W2, const float* __restrict__ B2,
    float* __restrict__ Y, float* __restrict__ S1, float* __restrict__ S2)
{
    __shared__ float wls[64], w1s[64], w2s[64];
    const int tid = threadIdx.x;
    if (tid < 64) { wls[tid] = Wl[tid]; w1s[tid] = W1[tid]; w2s[tid] = W2[tid]; }
    __syncthreads();
    const int n = blockIdx.x * 256 + tid;
    if (n >= NNODES) return;
    const float4* xr = reinterpret_cast<const float4*>(X + (size_t)n * H);
    float aL = 0.f, a1 = 0.f, a2 = 0.f;
    #pragma unroll
    for (int kv = 0; kv < 16; ++kv) {
        float4 xv = xr[kv];
        int k = kv * 4;
        aL = fmaf(xv.x, wls[k + 0], aL); a1 = fmaf(xv.x, w1s[k + 0], a1); a2 = fmaf(xv.x, w2s[k + 0], a2);
        aL = fmaf(xv.y, wls[k + 1], aL); a1 = fmaf(xv.y, w1s[k + 1], a1); a2 = fmaf(xv.y, w2s[k + 1], a2);
        aL = fmaf(xv.z, wls[k + 2], aL); a1 = fmaf(xv.z, w1s[k + 2], a1); a2 = fmaf(xv.z, w2s[k + 2], a2);
        aL = fmaf(xv.w, wls[k + 3], aL); a1 = fmaf(xv.w, w1s[k + 3], a1); a2 = fmaf(xv.w, w2s[k + 3], a2);
    }
    float bias = Bl[0] + B1[0] + B2[0];
    Y[n] = aL + bias; S1[n] = a1; S2[n] = a2;
}

// ---------------------------------------------------------------------------
// Two-pass counting sort -> full CSR by dst.
// Pass 1 (coarse): 3125 buckets of 64 nodes; cursor frontier ~400 KB is
// L2-resident so sorted-array writes fill whole lines (no amplification).
// Pass 2 (refine): per bucket, LDS-staged 64-bin counting sort, in-place
// write-back + fine row_ptr emission.
// ---------------------------------------------------------------------------
__global__ __launch_bounds__(256) void hist_coarse_kernel(
    const int* __restrict__ dst1, const int* __restrict__ dst2,
    int* __restrict__ cnt)   // cnt[2*NCB]
{
    const int* dst = blockIdx.y ? dst2 : dst1;
    int* c = cnt + blockIdx.y * NCB;
    const int t = blockIdx.x * 256 + threadIdx.x;
    const int tot = gridDim.x * 256;
    const int4* d4 = reinterpret_cast<const int4*>(dst);
    for (int q = t; q < NE / 4; q += tot) {
        int4 v = d4[q];
        atomicAdd(&c[v.x >> 6], 1);
        atomicAdd(&c[v.y >> 6], 1);
        atomicAdd(&c[v.z >> 6], 1);
        atomicAdd(&c[v.w >> 6], 1);
    }
}

__global__ __launch_bounds__(1024) void scan_coarse_kernel(
    const int* __restrict__ cnt, int* __restrict__ cbase, int* __restrict__ ccur)
{
    const int set = blockIdx.x;
    const int* c = cnt + set * NCB;
    int* b = cbase + set * (NCB + 1);
    int* cu = ccur + set * NCB;
    __shared__ int part[1024];
    const int t = threadIdx.x;
    const int lo = t * 4;
    int v[4]; int s = 0;
    #pragma unroll
    for (int j = 0; j < 4; ++j) {
        int i = lo + j;
        v[j] = (i < NCB) ? c[i] : 0;
        s += v[j];
    }
    part[t] = s;
    __syncthreads();
    for (int off = 1; off < 1024; off <<= 1) {
        int u = (t >= off) ? part[t - off] : 0;
        __syncthreads();
        part[t] += u;
        __syncthreads();
    }
    int run = part[t] - s;   // exclusive chunk prefix
    #pragma unroll
    for (int j = 0; j < 4; ++j) {
        int i = lo + j;
        if (i < NCB) { b[i] = run; cu[i] = run; run += v[j]; }
    }
    if (t == 1023) b[NCB] = part[1023];
}

__global__ __launch_bounds__(256) void place_coarse_kernel(
    const int* __restrict__ ei1, const float* __restrict__ ew1,
    const int* __restrict__ ei2, const float* __restrict__ ew2,
    int* __restrict__ ccur, uint2* __restrict__ E1, uint2* __restrict__ E2)
{
    const int set = blockIdx.y;
    const int* EI = set ? ei2 : ei1;
    const float* EW = set ? ew2 : ew1;
    int* cur = ccur + set * NCB;
    uint2* E = set ? E2 : E1;
    const int t = blockIdx.x * 256 + threadIdx.x;
    const int tot = gridDim.x * 256;
    const int4* s4 = reinterpret_cast<const int4*>(EI);
    const int4* d4 = reinterpret_cast<const int4*>(EI + NE);
    const float4* w4 = reinterpret_cast<const float4*>(EW);
    for (int q = t; q < NE / 4; q += tot) {
        int4 s = s4[q];
        int4 d = d4[q];
        float4 w = w4[q];
        int p0 = atomicAdd(&cur[d.x >> 6], 1);
        int p1 = atomicAdd(&cur[d.y >> 6], 1);
        int p2 = atomicAdd(&cur[d.z >> 6], 1);
        int p3 = atomicAdd(&cur[d.w >> 6], 1);
        E[p0] = make_uint2((unsigned)s.x | ((unsigned)(d.x & 63) << 18), __float_as_uint(w.x));
        E[p1] = make_uint2((unsigned)s.y | ((unsigned)(d.y & 63) << 18), __float_as_uint(w.y));
        E[p2] = make_uint2((unsigned)s.z | ((unsigned)(d.z & 63) << 18), __float_as_uint(w.z));
        E[p3] = make_uint2((unsigned)s.w | ((unsigned)(d.w & 63) << 18), __float_as_uint(w.w));
    }
}

// Refine: per-bucket LDS counting sort (in-place) + fine row_ptr.
__global__ __launch_bounds__(256) void refine_kernel(
    uint2* __restrict__ E1, uint2* __restrict__ E2,
    const int* __restrict__ cbase,
    int* __restrict__ rp1, int* __restrict__ rp2)
{
    const int set = blockIdx.y;
    uint2* E = set ? E2 : E1;
    const int* cb = cbase + set * (NCB + 1);
    int* rp = set ? rp2 : rp1;
    const int b = blockIdx.x;
    const int lo = cb[b];
    const int n = cb[b + 1] - lo;

    __shared__ uint2 st[RCAP];
    __shared__ int h[64], off[64], cur[64];
    const int tid = threadIdx.x;
    if (tid < 64) h[tid] = 0;
    __syncthreads();
    for (int i = tid; i < n; i += 256) {
        uint2 p = E[lo + i];
        st[i] = p;
        atomicAdd(&h[(p.x >> 18) & 63], 1);
    }
    __syncthreads();
    if (tid == 0) {
        int run = 0;
        #pragma unroll
        for (int j = 0; j < 64; ++j) { off[j] = run; cur[j] = run; run += h[j]; }
    }
    __syncthreads();
    if (tid < 64) rp[b * 64 + tid] = lo + off[tid];
    if (b == NCB - 1 && tid == 0) rp[NNODES] = cb[NCB];
    for (int i = tid; i < n; i += 256) {
        uint2 p = st[i];
        int pos = atomicAdd(&cur[(p.x >> 18) & 63], 1);
        E[lo + pos] = make_uint2(p.x & SRC_MASK, p.y);
    }
}

// ---------------------------------------------------------------------------
// CSR SpMV aggregation, 64 features, fp16 source values.
// One wave per dst row, 8 rows/wave; row extents prefetched; 8-deep unroll.
// ---------------------------------------------------------------------------
__global__ __launch_bounds__(256) void csr_accum64_kernel(
    const uint2* __restrict__ E1, const int* __restrict__ rp1,
    const uint2* __restrict__ E2, const int* __restrict__ rp2,
    const __half* __restrict__ S1, const __half* __restrict__ S2,
    float* __restrict__ Y)
{
    const int lane = threadIdx.x & 63;
    const int wid = (blockIdx.x * 256 + threadIdx.x) >> 6;
    const int r0 = wid * 8;   // 25000 waves x 8 rows = 200000

    int b1[9], b2[9];
    #pragma unroll
    for (int i = 0; i < 9; ++i) b1[i] = rp1[r0 + i];
    #pragma unroll
    for (int i = 0; i < 9; ++i) b2[i] = rp2[r0 + i];

    #pragma unroll 1
    for (int r = 0; r < 8; ++r) {
        float acc = 0.f;
        {
            int e = b1[r];
            const int hi = b1[r + 1];
            for (; e + 8 <= hi; e += 8) {
                uint2 p[8];
                float v[8];
                #pragma unroll
                for (int j = 0; j < 8; ++j) p[j] = E1[e + j];
                #pragma unroll
                for (int j = 0; j < 8; ++j)
                    v[j] = __half2float(S1[(size_t)p[j].x * H + lane]);
                #pragma unroll
                for (int j = 0; j < 8; ++j)
                    acc = fmaf(__uint_as_float(p[j].y), v[j], acc);
            }
            for (; e < hi; ++e) {
                uint2 p = E1[e];
                acc = fmaf(__uint_as_float(p.y),
                           __half2float(S1[(size_t)p.x * H + lane]), acc);
            }
        }
        {
            int e = b2[r];
            const int hi = b2[r + 1];
            for (; e + 8 <= hi; e += 8) {
                uint2 p[8];
                float v[8];
                #pragma unroll
                for (int j = 0; j < 8; ++j) p[j] = E2[e + j];
                #pragma unroll
                for (int j = 0; j < 8; ++j)
                    v[j] = __half2float(S2[(size_t)p[j].x * H + lane]);
                #pragma unroll
                for (int j = 0; j < 8; ++j)
                    acc = fmaf(__uint_as_float(p[j].y), v[j], acc);
            }
            for (; e < hi; ++e) {
                uint2 p = E2[e];
                acc = fmaf(__uint_as_float(p.y),
                           __half2float(S2[(size_t)p.x * H + lane]), acc);
            }
        }
        Y[(size_t)(r0 + r) * H + lane] += acc;
    }
}

// ---------------------------------------------------------------------------
// Block-3 CSR aggregation (scalar, fp32) + fused readout.
// ---------------------------------------------------------------------------
__device__ __forceinline__ unsigned fkey(float v) {
    unsigned u = __float_as_uint(v);
    return (u & 0x80000000u) ? ~u : (u | 0x80000000u);
}

__global__ __launch_bounds__(256) void csr_accum1_readout_kernel(
    const uint2* __restrict__ E1, const int* __restrict__ rp1,
    const uint2* __restrict__ E2, const int* __restrict__ rp2,
    const float* __restrict__ s1, const float* __restrict__ s2,
    const float* __restrict__ Y3,
    float* __restrict__ body1, float* __restrict__ body2,
    unsigned int* __restrict__ keys)
{
    __shared__ unsigned int smax[4];
    const int tid = threadIdx.x;
    if (tid < 4) smax[tid] = 0u;
    __syncthreads();
    const int r = blockIdx.x * 256 + tid;
    if (r < NNODES) {
        float acc = Y3[r];
        for (int e = rp1[r]; e < rp1[r + 1]; ++e) {
            uint2 p = E1[e];
            acc = fmaf(__uint_as_float(p.y), s1[p.x], acc);
        }
        for (int e = rp2[r]; e < rp2[r + 1]; ++e) {
            uint2 p = E2[e];
            acc = fmaf(__uint_as_float(p.y), s2[p.x], acc);
        }
        body1[r] = acc;
        body2[r] = acc;
        atomicMax(&smax[r / NGRAPH_NODES], fkey(acc));
    }
    __syncthreads();
    if (tid < 4 && smax[tid]) atomicMax(&keys[tid], smax[tid]);
}

__global__ void finalize_kernel(const unsigned int* __restrict__ keys,
                                float* __restrict__ out)
{
    int i = threadIdx.x;
    if (i < 4) {
        unsigned k = keys[i];
        unsigned u = (k & 0x80000000u) ? (k ^ 0x80000000u) : ~k;
        out[i] = __uint_as_float(u);
    }
}

// ---------------------------------------------------------------------------
// Fallback (atomic) scatters — used only if ws_size is too small.
// ---------------------------------------------------------------------------
__global__ __launch_bounds__(256) void scatter64_kernel(
    const int* __restrict__ EI, const float* __restrict__ EW,
    const float* __restrict__ S, float* __restrict__ Y)
{
    const int lane = threadIdx.x & 63;
    const int wid = (blockIdx.x * 256 + threadIdx.x) >> 6;
    const int nw = (gridDim.x * 256) >> 6;
    for (int e = wid; e < NE; e += nw) {
        int s = EI[e];
        int d = EI[NE + e];
        float w = EW[e];
        float v = S[(size_t)s * H + lane];
        unsafeAtomicAdd(&Y[(size_t)d * H + lane], w * v);
    }
}

__global__ __launch_bounds__(256) void scatter1_kernel(
    const int* __restrict__ EI, const float* __restrict__ EW,
    const float* __restrict__ S, float* __restrict__ Y)
{
    const int t = blockIdx.x * 256 + threadIdx.x;
    const int tot = gridDim.x * 256;
    for (int e = t; e < NE; e += tot) {
        int s = EI[e];
        int d = EI[NE + e];
        float w = EW[e];
        unsafeAtomicAdd(&Y[d], w * S[s]);
    }
}

__global__ __launch_bounds__(256) void readout_kernel(
    const float* __restrict__ Y3, float* __restrict__ body1,
    float* __restrict__ body2, unsigned int* __restrict__ keys)
{
    __shared__ unsigned int smax[4];
    const int tid = threadIdx.x;
    if (tid < 4) smax[tid] = 0u;
    __syncthreads();
    const int i = blockIdx.x * 256 + tid;
    if (i < NNODES) {
        float v = Y3[i];
        body1[i] = v;
        body2[i] = v;
        atomicMax(&smax[i / NGRAPH_NODES], fkey(v));
    }
    __syncthreads();
    if (tid < 4 && smax[tid]) atomicMax(&keys[tid], smax[tid]);
}

// ---------------------------------------------------------------------------
extern "C" void kernel_launch(void* const* d_in, const int* in_sizes, int n_in,
                              void* d_out, int out_size, void* d_ws, size_t ws_size,
                              hipStream_t stream)
{
    const float* x   = (const float*)d_in[0];
    const int*   ei  = (const int*)d_in[1];
    const float* ew  = (const float*)d_in[2];
    const int*   ei2 = (const int*)d_in[3];
    const float* ew2 = (const float*)d_in[4];
    const float* W[18];
    for (int i = 0; i < 18; ++i) W[i] = (const float*)d_in[6 + i];

    // S1/S2 sized for the fp32 fallback (fp16 fast path uses half the space)
    float* Y  = (float*)d_ws;                       // 200000 x 64 f32
    float* S1 = Y + (size_t)NNODES * H;             // 200000 x 64 f32 (or f16)
    float* S2 = S1 + (size_t)NNODES * H;
    float* Y3 = S2 + (size_t)NNODES * H;            // 200000 f32
    uint2* E1 = (uint2*)(Y3 + NNODES);              // NE uint2
    uint2* E2 = E1 + NE;
    unsigned int* keys = (unsigned int*)(E2 + NE);  // 4
    int* cnt   = (int*)(keys + 4);                  // 2*NCB
    int* cbase = cnt + 2 * NCB;                     // 2*(NCB+1)
    int* ccur  = cbase + 2 * (NCB + 1);             // 2*NCB
    int* rp1   = ccur + 2 * NCB;                    // NNODES+1
    int* rp2   = rp1 + NNODES + 1;                  // NNODES+1
    size_t needed = (size_t)((char*)(rp2 + NNODES + 1) - (char*)d_ws);

    __half* hS1 = (__half*)S1;
    __half* hS2 = (__half*)S2;

    float* out = (float*)d_out;   // [0..3]=graph max, then x twice

    if (ws_size >= needed) {
        // zero keys + coarse histograms in one memset
        hipMemsetAsync(keys, 0, (size_t)(4 + 2 * NCB) * sizeof(int), stream);

        // Two-pass counting sort -> CSR (built once, reused by all 3 blocks)
        hist_coarse_kernel<<<dim3(1024, 2), 256, 0, stream>>>(ei + NE, ei2 + NE, cnt);
        scan_coarse_kernel<<<2, 1024, 0, stream>>>(cnt, cbase, ccur);
        place_coarse_kernel<<<dim3(1024, 2), 256, 0, stream>>>(
            ei, ew, ei2, ew2, ccur, E1, E2);
        refine_kernel<<<dim3(NCB, 2), 256, 0, stream>>>(E1, E2, cbase, rp1, rp2);

        // Block 1
        gemm3_kernel<128, __half><<<NNODES / 32, 256, 0, stream>>>(
            x, W[0], W[1], W[2], W[3], W[4], W[5], Y, hS1, hS2);
        csr_accum64_kernel<<<6250, 256, 0, stream>>>(E1, rp1, E2, rp2, hS1, hS2, Y);

        // Block 2 (in-place on Y)
        gemm3_kernel<64, __half><<<NNODES / 32, 256, 0, stream>>>(
            Y, W[6], W[7], W[8], W[9], W[10], W[11], Y, hS1, hS2);
        csr_accum64_kernel<<<6250, 256, 0, stream>>>(E1, rp1, E2, rp2, hS1, hS2, Y);

        // Block 3 (S1/S2 reused as [NNODES] f32 scalars) + fused readout
        gemm3_out1_kernel<<<(NNODES + 255) / 256, 256, 0, stream>>>(
            Y, W[12], W[13], W[14], W[15], W[16], W[17], Y3, S1, S2);
        csr_accum1_readout_kernel<<<(NNODES + 255) / 256, 256, 0, stream>>>(
            E1, rp1, E2, rp2, S1, S2, Y3, out + 4, out + 4 + NNODES, keys);
        finalize_kernel<<<1, 64, 0, stream>>>(keys, out);
    } else {
        unsigned int* okeys = (unsigned int*)(Y3 + NNODES);
        hipMemsetAsync(okeys, 0, 4 * sizeof(unsigned int), stream);

        gemm3_kernel<128, float><<<NNODES / 32, 256, 0, stream>>>(
            x, W[0], W[1], W[2], W[3], W[4], W[5], Y, S1, S2);
        scatter64_kernel<<<2048, 256, 0, stream>>>(ei,  ew,  S1, Y);
        scatter64_kernel<<<2048, 256, 0, stream>>>(ei2, ew2, S2, Y);

        gemm3_kernel<64, float><<<NNODES / 32, 256, 0, stream>>>(
            Y, W[6], W[7], W[8], W[9], W[10], W[11], Y, S1, S2);
        scatter64_kernel<<<2048, 256, 0, stream>>>(ei,  ew,  S1, Y);
        scatter64_kernel<<<2048, 256, 0, stream>>>(ei2, ew2, S2, Y);

        gemm3_out1_kernel<<<(NNODES + 255) / 256, 256, 0, stream>>>(
            Y, W[12], W[13], W[14], W[15], W[16], W[17], Y3, S1, S2);
        scatter1_kernel<<<2048, 256, 0, stream>>>(ei,  ew,  S1, Y3);
        scatter1_kernel<<<2048, 256, 0, stream>>>(ei2, ew2, S2, Y3);

        readout_kernel<<<(NNODES + 255) / 256, 256, 0, stream>>>(
            Y3, out + 4, out + 4 + NNODES, okeys);
        finalize_kernel<<<1, 64, 0, stream>>>(okeys, out);
    }
}